// Round 4
// baseline (439.390 us; speedup 1.0000x reference)
//
#include <hip/hip_runtime.h>
#include <hip/hip_bf16.h>
#include <math.h>

// B=2 QL=512 KL=8192 D=1024 H=8 HD=128
typedef __attribute__((ext_vector_type(4))) float fx4;
typedef __attribute__((ext_vector_type(4))) short sx4;
typedef __attribute__((ext_vector_type(8))) short sx8;
typedef unsigned long long u64;

#define MFMA16(a, b, c) __builtin_amdgcn_mfma_f32_16x16x16bf16_1k(a, b, c, 0, 0, 0)
#define MFMA32(a, b, c) __builtin_amdgcn_mfma_f32_16x16x32_bf16(a, b, c, 0, 0, 0)

__device__ __forceinline__ unsigned short f2bf(float f) {
  unsigned int u = __float_as_uint(f);
  return (unsigned short)((u + 0x7fffu + ((u >> 16) & 1u)) >> 16);  // RNE
}

__device__ __forceinline__ sx4 pk4(const fx4 v) {
  sx4 o;
  o[0] = (short)f2bf(v[0]); o[1] = (short)f2bf(v[1]);
  o[2] = (short)f2bf(v[2]); o[3] = (short)f2bf(v[3]);
  return o;
}

// async global->LDS, 16B per lane; LDS dest is wave-uniform base + lane*16
typedef const __attribute__((address_space(1))) char* gc1p;
typedef __attribute__((address_space(3))) char* lc3p;
__device__ __forceinline__ void glds16(const void* g, const void* lds_uniform) {
  gc1p gp = (gc1p)(unsigned long long)(uintptr_t)g;
  lc3p lp = (lc3p)(unsigned)__builtin_amdgcn_readfirstlane((int)(unsigned)(uintptr_t)lds_uniform);
  __builtin_amdgcn_global_load_lds(gp, lp, 16, 0, 0);
}

// ---------------- weight convert: 4 tensors of 1M f32 each -------------------
__global__ __launch_bounds__(256) void k_conv4(const float* s0, const float* s1,
                                               const float* s2, const float* s3,
                                               short* d0, short* d1, short* d2,
                                               short* d3) {
  const int seg = blockIdx.x >> 9;
  const float* s = seg == 0 ? s0 : seg == 1 ? s1 : seg == 2 ? s2 : s3;
  short* d = seg == 0 ? d0 : seg == 1 ? d1 : seg == 2 ? d2 : d3;
  size_t i = (size_t)(blockIdx.x & 511) * 2048 + (size_t)threadIdx.x * 8;
  const fx4 a = *(const fx4*)(s + i);
  const fx4 b = *(const fx4*)(s + i + 4);
  sx8 o;
  o[0] = (short)f2bf(a[0]); o[1] = (short)f2bf(a[1]);
  o[2] = (short)f2bf(a[2]); o[3] = (short)f2bf(a[3]);
  o[4] = (short)f2bf(b[0]); o[5] = (short)f2bf(b[1]);
  o[6] = (short)f2bf(b[2]); o[7] = (short)f2bf(b[3]);
  *(sx8*)(d + i) = o;
}

// ---------------- mask pack: int32 [2,512,8192] -> u64 bitmask ---------------
// 16B/lane loads; nibble assembly through LDS.
__global__ __launch_bounds__(256) void k_pack_mask(const int* __restrict__ mask,
                                                   u64* __restrict__ mb) {
  __shared__ unsigned char nib[256];
  const int t = threadIdx.x;
  const int4 m = *(const int4*)(mask + (size_t)blockIdx.x * 1024 + t * 4);
  nib[t] = (unsigned char)((m.x != 0) | ((m.y != 0) << 1) | ((m.z != 0) << 2) |
                           ((m.w != 0) << 3));
  __syncthreads();
  if (t < 16) {
    u64 wv = 0;
#pragma unroll
    for (int i = 0; i < 16; i++) wv |= (u64)(nib[t * 16 + i] & 0xF) << (4 * i);
    mb[(size_t)blockIdx.x * 16 + t] = wv;
  }
}

// ---------------- GEMM: C = alpha*(A[M,K] @ B[N,K]^T + bias) -----------------
// MODE 0: bf16 row-major C.  MODE 1: f32 row-major C.
// MODE 2: bf16 V^T output Vt[b][d][kl] with 8B-half swap when (d&8).
// AF32: A is f32, converted to bf16 during VGPR staging (loads for iter i+1
// issued after the consume barrier so they overlap compute).
// Big-M GEMMs: XCD-aware swizzle (8 n-tiles of an m-strip on one XCD).
template <int MODE, bool AF32>
__global__ __launch_bounds__(256) void k_gemm(const void* __restrict__ Aptr,
                                              const short* __restrict__ Bw,
                                              const float* __restrict__ bias,
                                              void* __restrict__ Cptr,
                                              int M, int N, int K, float alpha) {
  __shared__ __align__(16) short sA[8192];  // 128 rows x 64, swizzled 16B blocks
  __shared__ __align__(16) short sB[8192];
  const int t = threadIdx.x;
  const int lane = t & 63;
  const int w = t >> 6;
  const int quad = lane >> 4;
  const int l16 = lane & 15;
  const int x7 = l16 & 7;
  int m0, n0;
  if (M >= 8192) {  // ntile==8: blocks sharing the A strip land on one XCD
    const int ml = blockIdx.x & 7, nn = (blockIdx.x >> 3) & 7, mh = blockIdx.x >> 6;
    m0 = (mh * 8 + ml) << 7;
    n0 = nn << 7;
  } else {
    const int ntile = N >> 7;
    n0 = (blockIdx.x % ntile) << 7;
    m0 = (blockIdx.x / ntile) << 7;
  }
  const int wm = (w >> 1) << 6;
  const int wn = (w & 1) << 6;
  const fx4 fzero = {0.f, 0.f, 0.f, 0.f};
  fx4 acc[4][4];
#pragma unroll
  for (int i = 0; i < 4; i++)
#pragma unroll
    for (int j = 0; j < 4; j++) acc[i][j] = fzero;

  const int srow = (lane >> 3);
  const int scb = lane & 7;
  // AF32 staging geometry
  const float* Af = (const float*)Aptr;
  const int arow = t >> 4;            // + p*16
  const int acol = (t & 15) * 4;      // f32 col
  const int acb = ((t & 15) >> 1) ^ (arow & 7);  // swizzled 16B block
  const int ahalf = ((t & 15) & 1) * 4;
  fx4 areg[8];
  if (AF32) {
#pragma unroll
    for (int p = 0; p < 8; p++)
      areg[p] = *(const fx4*)(Af + (size_t)(m0 + arow + p * 16) * K + acol);
  }

  for (int k0 = 0; k0 < K; k0 += 64) {
    __syncthreads();
    if (AF32) {
#pragma unroll
      for (int p = 0; p < 8; p++) {
        const int row = arow + p * 16;
        *(sx4*)(&sA[row * 64 + acb * 8 + ahalf]) = pk4(areg[p]);
      }
    } else {
      const short* Ab = (const short*)Aptr;
#pragma unroll
      for (int j = 0; j < 4; j++) {
        const int row = w * 32 + j * 8 + srow;
        const int cb = scb ^ (row & 7);
        glds16(Ab + (size_t)(m0 + row) * K + k0 + cb * 8, &sA[(w * 32 + j * 8) * 64]);
      }
    }
#pragma unroll
    for (int j = 0; j < 4; j++) {
      const int row = w * 32 + j * 8 + srow;
      const int cb = scb ^ (row & 7);
      glds16(Bw + (size_t)(n0 + row) * K + k0 + cb * 8, &sB[(w * 32 + j * 8) * 64]);
    }
    __syncthreads();
    if (AF32) {  // prefetch next A tile into regs; overlaps with compute below
      const int kn = (k0 + 64 < K) ? k0 + 64 : k0;
#pragma unroll
      for (int p = 0; p < 8; p++)
        areg[p] = *(const fx4*)(Af + (size_t)(m0 + arow + p * 16) * K + kn + acol);
    }
#pragma unroll
    for (int kc = 0; kc < 2; kc++) {
      const int cbp = ((kc * 4 + quad) ^ x7) * 8;
      sx8 fa[4], fb[4];
#pragma unroll
      for (int i = 0; i < 4; i++) {
        fa[i] = *(const sx8*)(&sA[(wm + i * 16 + l16) * 64 + cbp]);
        fb[i] = *(const sx8*)(&sB[(wn + i * 16 + l16) * 64 + cbp]);
      }
#pragma unroll
      for (int mi = 0; mi < 4; mi++)
#pragma unroll
        for (int ni = 0; ni < 4; ni++)
          acc[mi][ni] = MFMA32(fa[mi], fb[ni], acc[mi][ni]);
    }
  }
  // epilogue: C/D layout col=lane&15, row=quad*4+reg
#pragma unroll
  for (int ni = 0; ni < 4; ni++) {
    const int col = n0 + wn + ni * 16 + l16;
    const float bval = bias[col];
    if (MODE == 2) {
#pragma unroll
      for (int mi = 0; mi < 4; mi++) {
        const int rowb = m0 + wm + mi * 16 + quad * 4;
        const int bb = rowb >> 13;
        const int kl = (rowb & 8191) ^ ((col & 8) ? 4 : 0);
        sx4 pkv;
#pragma unroll
        for (int r = 0; r < 4; r++) pkv[r] = (short)f2bf(acc[mi][ni][r] + bval);
        *(sx4*)((unsigned short*)Cptr + ((size_t)bb * 1024 + col) * 8192 + kl) = pkv;
      }
    } else {
#pragma unroll
      for (int mi = 0; mi < 4; mi++)
#pragma unroll
        for (int r = 0; r < 4; r++) {
          const int row = m0 + wm + mi * 16 + quad * 4 + r;
          const float v = (acc[mi][ni][r] + bval) * alpha;
          if (MODE == 1) ((float*)Cptr)[(size_t)row * N + col] = v;
          else ((unsigned short*)Cptr)[(size_t)row * N + col] = f2bf(v);
        }
    }
  }
}

// ---------------- flash attention (S^T trick, no-max softmax) ----------------
// grid 1024, XCD-swizzled: x = (g&7) + 8*(qt + 8*(g>>3)), g=(b*8+h)*8+s.
// All 8 qt-WGs of a (b,h,s) group share x%8 -> same XCD -> K/V chunk L2-reused.
__global__ __launch_bounds__(256, 4) void k_attn(const short* __restrict__ Qp,
                                                 const short* __restrict__ Kp,
                                                 const short* __restrict__ Vt,
                                                 const u64* __restrict__ mb,
                                                 float* __restrict__ ml,
                                                 float* __restrict__ Op) {
  __shared__ __align__(16) short sK[8192];  // 64 keys x 128 d (256B rows, swizzled)
  __shared__ __align__(16) short sV[8192];  // 128 d x 64 keys (128B rows, swizzled)
  const int x = blockIdx.x;
  const int gl = x & 7;
  const int qt = (x >> 3) & 7;
  const int gh = x >> 6;
  const int g = gh * 8 + gl;  // 0..127
  const int s = g & 7;
  const int h = (g >> 3) & 7;
  const int b = g >> 6;
  const int li = ((b * 8 + h) * 8 + qt) * 8 + s;  // logical index for ml/Op
  const int t = threadIdx.x;
  const int lane = t & 63;
  const int w = t >> 6;
  const int quad = lane >> 4;
  const int l16 = lane & 15;
  const int x7 = l16 & 7;
  const int q0 = qt << 6;
  const fx4 fzero = {0.f, 0.f, 0.f, 0.f};

  const short* qbase = Qp + (size_t)(b * 512 + q0 + w * 16 + l16) * 1024 + h * 128;
  sx8 aq[4];
#pragma unroll
  for (int kc = 0; kc < 4; kc++) aq[kc] = *(const sx8*)(qbase + kc * 32 + quad * 8);

  fx4 Ot[8];
#pragma unroll
  for (int d = 0; d < 8; d++) Ot[d] = fzero;
  float lsum = 0.f;

  const short* kbase = Kp + (size_t)(b * 8192 + s * 1024) * 1024 + h * 128;
  const short* vbase = Vt + (size_t)(b * 1024 + h * 128) * 8192 + s * 1024;
  const u64* wdp = mb + (size_t)(b * 512 + q0 + w * 16 + l16) * 128 + s * 16;
  const int srow4 = lane >> 4, scb16 = lane & 15;
  const int srow8 = lane >> 3, scb8 = lane & 7;
  const int h4 = ((quad & 1) ^ ((l16 >> 3) & 1)) * 4;  // 8B-half parity (bank spread)

  for (int kt = 0; kt < 16; kt++) {
    __syncthreads();
#pragma unroll
    for (int j = 0; j < 4; j++) {  // K tile: 4 rows/issue
      const int row = (w * 4 + j) * 4 + srow4;
      const int cb = scb16 ^ (row & 7);
      glds16(kbase + (size_t)(kt * 64 + row) * 1024 + cb * 8, &sK[(w * 4 + j) * 512]);
    }
#pragma unroll
    for (int j = 0; j < 4; j++) {  // V^T tile: 8 rows/issue
      const int row = (w * 4 + j) * 8 + srow8;
      const int cb = scb8 ^ (row & 7);
      glds16(vbase + (size_t)row * 8192 + kt * 64 + cb * 8, &sV[(w * 4 + j) * 512]);
    }
    const u64 wd = wdp[kt];
    __syncthreads();
    const unsigned lo = (unsigned)wd, hi = (unsigned)(wd >> 32);
    sx4 pk[4];
#pragma unroll
    for (int nt = 0; nt < 4; nt++) {
      fx4 a = fzero;
#pragma unroll
      for (int kc = 0; kc < 4; kc++) {
        const sx8 kf = *(const sx8*)(&sK[(nt * 16 + l16) * 128 + ((kc * 4 + quad) ^ x7) * 8]);
        a = MFMA32(kf, aq[kc], a);  // S^T: row=key, col=q
      }
      const unsigned bits = (nt & 2) ? hi : lo;
      const int sh = (nt & 1) * 16 + quad * 4;
      float pv[4];
#pragma unroll
      for (int r = 0; r < 4; r++) {
        const float e = __builtin_amdgcn_exp2f(a[r]);  // scale*log2e folded into Qp
        pv[r] = ((bits >> (sh + r)) & 1u) ? e : 0.f;
        lsum += pv[r];
      }
      sx4 pko;
      ((unsigned*)&pko)[0] = __builtin_amdgcn_perm(
          __float_as_uint(pv[1]) + 0x8000u, __float_as_uint(pv[0]) + 0x8000u, 0x07060302u);
      ((unsigned*)&pko)[1] = __builtin_amdgcn_perm(
          __float_as_uint(pv[3]) + 0x8000u, __float_as_uint(pv[2]) + 0x8000u, 0x07060302u);
      pk[nt] = pko;
    }
#pragma unroll
    for (int dt = 0; dt < 8; dt++) {
      fx4 o = Ot[dt];
#pragma unroll
      for (int nt = 0; nt < 4; nt++) {
        const int cb = (2 * nt + (quad >> 1)) ^ x7;
        const sx4 vf = *(const sx4*)(&sV[(dt * 16 + l16) * 64 + cb * 8 + h4]);
        o = MFMA16(vf, pk[nt], o);  // O^T: row=d, col=q
      }
      Ot[dt] = o;
    }
  }
  lsum += __shfl_xor(lsum, 16, 64);
  lsum += __shfl_xor(lsum, 32, 64);
  if (lane < 16) ml[(size_t)li * 64 + w * 16 + l16] = lsum;
  float* ob = Op + (size_t)li * 8192 + (w * 16 + l16) * 128 + quad * 4;
#pragma unroll
  for (int dt = 0; dt < 8; dt++) *(fx4*)(ob + dt * 16) = Ot[dt];
}

// ---------------- combine 8 KL-split partials -> summed bf16 -----------------
__global__ __launch_bounds__(256) void k_combine(const float* __restrict__ ml,
                                                 const float* __restrict__ Op,
                                                 short* __restrict__ summed) {
  const int xc = blockIdx.x;  // qt + 8*h + 64*b
  const int qt = xc & 7;
  const int h = (xc >> 3) & 7;
  const int b = xc >> 6;
  const int t = threadIdx.x;
  const int row = t >> 2;
  const int dg = (t & 3) * 32;
  float L = 0.f;
#pragma unroll
  for (int s = 0; s < 8; s++) L += ml[(size_t)(xc * 8 + s) * 64 + row];
  float o[32];
#pragma unroll
  for (int i = 0; i < 32; i++) o[i] = 0.f;
  if (L != 0.f) {
#pragma unroll
    for (int s = 0; s < 8; s++) {
      const float* src = Op + (size_t)(xc * 8 + s) * 8192 + row * 128 + dg;
#pragma unroll
      for (int i = 0; i < 8; i++) {
        const fx4 v = *(const fx4*)(src + i * 4);
        o[i * 4 + 0] += v[0]; o[i * 4 + 1] += v[1];
        o[i * 4 + 2] += v[2]; o[i * 4 + 3] += v[3];
      }
    }
    const float inv = 1.f / L;
#pragma unroll
    for (int i = 0; i < 32; i++) o[i] *= inv;
  }
  short* dst = summed + (size_t)(b * 512 + qt * 64 + row) * 1024 + h * 128 + dg;
#pragma unroll
  for (int i = 0; i < 4; i++) {
    sx8 pkv;
#pragma unroll
    for (int j = 0; j < 8; j++) pkv[j] = (short)f2bf(o[i * 8 + j]);
    *(sx8*)(dst + i * 8) = pkv;
  }
}

// ---------------- host ------------------------------------------------------
extern "C" void kernel_launch(void* const* d_in, const int* in_sizes, int n_in,
                              void* d_out, int out_size, void* d_ws, size_t ws_size,
                              hipStream_t stream) {
  (void)in_sizes; (void)n_in; (void)out_size; (void)ws_size;
  const float* inq = (const float*)d_in[0];
  const float* ink = (const float*)d_in[1];
  const float* inv = (const float*)d_in[2];
  const int* mask = (const int*)d_in[3];
  const float* Wq = (const float*)d_in[4];
  const float* bq = (const float*)d_in[5];
  const float* Wk = (const float*)d_in[6];
  const float* bk = (const float*)d_in[7];
  const float* Wv = (const float*)d_in[8];
  const float* bv = (const float*)d_in[9];
  const float* Wf = (const float*)d_in[10];
  const float* bf = (const float*)d_in[11];

  char* ws = (char*)d_ws;
  float* Op = (float*)(ws + 0);            // 33.5MB [1024][64][128] f32
  short* Kp = (short*)(ws + 33554432);     // 33.5MB bf16
  short* Vt = (short*)(ws + 67108864);     // 33.5MB bf16 [2][1024][8192]
  short* cwq = (short*)(ws + 100663296);   // 2MB each
  short* cwk = (short*)(ws + 102760448);
  short* cwv = (short*)(ws + 104857600);
  short* cwf = (short*)(ws + 106954752);
  short* Qp = (short*)(ws + 109051904);
  short* summed = (short*)(ws + 111149056);
  u64* mb = (u64*)(ws + 113246208);
  float* ml = (float*)(ws + 114294784);

  const float alpha_q = 0.12751757f;  // (1/sqrt(128)) * log2(e)

  k_conv4<<<2048, 256, 0, stream>>>(Wq, Wk, Wv, Wf, cwq, cwk, cwv, cwf);
  k_pack_mask<<<8192, 256, 0, stream>>>(mask, mb);
  k_gemm<0, true><<<1024, 256, 0, stream>>>(ink, cwk, bk, Kp, 16384, 1024, 1024, 1.f);
  k_gemm<2, true><<<1024, 256, 0, stream>>>(inv, cwv, bv, Vt, 16384, 1024, 1024, 1.f);
  k_gemm<0, true><<<64, 256, 0, stream>>>(inq, cwq, bq, Qp, 1024, 1024, 1024, alpha_q);
  k_attn<<<1024, 256, 0, stream>>>(Qp, Kp, Vt, mb, ml, Op);
  k_combine<<<128, 256, 0, stream>>>(ml, Op, summed);
  k_gemm<1, false><<<64, 256, 0, stream>>>(summed, cwf, bf, (float*)d_out, 1024, 1024, 1024, 1.f);
}

// Round 5
// 404.498 us; speedup vs baseline: 1.0863x; 1.0863x over previous
//
#include <hip/hip_runtime.h>
#include <hip/hip_bf16.h>
#include <math.h>

// B=2 QL=512 KL=8192 D=1024 H=8 HD=128
typedef __attribute__((ext_vector_type(4))) float fx4;
typedef __attribute__((ext_vector_type(4))) short sx4;
typedef __attribute__((ext_vector_type(8))) short sx8;
typedef unsigned long long u64;

#define MFMA16(a, b, c) __builtin_amdgcn_mfma_f32_16x16x16bf16_1k(a, b, c, 0, 0, 0)
#define MFMA32(a, b, c) __builtin_amdgcn_mfma_f32_16x16x32_bf16(a, b, c, 0, 0, 0)

__device__ __forceinline__ unsigned short f2bf(float f) {
  unsigned int u = __float_as_uint(f);
  return (unsigned short)((u + 0x7fffu + ((u >> 16) & 1u)) >> 16);  // RNE
}

// async global->LDS, 16B per lane; LDS dest is wave-uniform base + lane*16
typedef const __attribute__((address_space(1))) char* gc1p;
typedef __attribute__((address_space(3))) char* lc3p;
__device__ __forceinline__ void glds16(const void* g, const void* lds_uniform) {
  gc1p gp = (gc1p)(unsigned long long)(uintptr_t)g;
  lc3p lp = (lc3p)(unsigned)__builtin_amdgcn_readfirstlane((int)(unsigned)(uintptr_t)lds_uniform);
  __builtin_amdgcn_global_load_lds(gp, lp, 16, 0, 0);
}

// ---------------- prep: all f32->bf16 conversions + mask pack ----------------
// [0,8192): ink -> ck            (16.8M elems)
// [8192,8704): inq -> cq         (1M)
// [8704,10752): Wq,Wk,Wv,Wf     (1M each)
// [10752,18944): mask pack
__global__ __launch_bounds__(256) void k_prep(
    const float* __restrict__ ink, const float* __restrict__ inq,
    const float* __restrict__ Wq, const float* __restrict__ Wk,
    const float* __restrict__ Wv, const float* __restrict__ Wf,
    const int* __restrict__ mask, short* ck, short* cq, short* cwq, short* cwk,
    short* cwv, short* cwf, u64* __restrict__ mb) {
  __shared__ unsigned char nib[256];
  const int bx = blockIdx.x;
  const int t = threadIdx.x;
  if (bx >= 10752) {  // mask pack: 16B/lane loads, nibble assembly via LDS
    const int mbx = bx - 10752;
    const int4 m = *(const int4*)(mask + (size_t)mbx * 1024 + t * 4);
    nib[t] = (unsigned char)((m.x != 0) | ((m.y != 0) << 1) | ((m.z != 0) << 2) |
                             ((m.w != 0) << 3));
    __syncthreads();
    if (t < 16) {
      u64 wv = 0;
#pragma unroll
      for (int i = 0; i < 16; i++) wv |= (u64)(nib[t * 16 + i] & 0xF) << (4 * i);
      mb[(size_t)mbx * 16 + t] = wv;
    }
    return;
  }
  const float* s;
  short* d;
  size_t i;
  if (bx < 8192) {
    s = ink; d = ck; i = (size_t)bx * 2048;
  } else if (bx < 8704) {
    s = inq; d = cq; i = (size_t)(bx - 8192) * 2048;
  } else {
    const int r = bx - 8704;
    const int seg = r >> 9;
    s = seg == 0 ? Wq : seg == 1 ? Wk : seg == 2 ? Wv : Wf;
    d = seg == 0 ? cwq : seg == 1 ? cwk : seg == 2 ? cwv : cwf;
    i = (size_t)(r & 511) * 2048;
  }
  i += (size_t)t * 8;
  const fx4 a = *(const fx4*)(s + i);
  const fx4 b = *(const fx4*)(s + i + 4);
  sx8 o;
  o[0] = (short)f2bf(a[0]); o[1] = (short)f2bf(a[1]);
  o[2] = (short)f2bf(a[2]); o[3] = (short)f2bf(a[3]);
  o[4] = (short)f2bf(b[0]); o[5] = (short)f2bf(b[1]);
  o[6] = (short)f2bf(b[2]); o[7] = (short)f2bf(b[3]);
  *(sx8*)(d + i) = o;
}

// ---------------- f32 -> bf16 convert (inv) ----------------------------------
__global__ __launch_bounds__(256) void k_conv(const float* __restrict__ s,
                                              short* __restrict__ d) {
  size_t i = ((size_t)blockIdx.x * 256 + threadIdx.x) * 8;
  const fx4 a = *(const fx4*)(s + i);
  const fx4 b = *(const fx4*)(s + i + 4);
  sx8 o;
  o[0] = (short)f2bf(a[0]); o[1] = (short)f2bf(a[1]);
  o[2] = (short)f2bf(a[2]); o[3] = (short)f2bf(a[3]);
  o[4] = (short)f2bf(b[0]); o[5] = (short)f2bf(b[1]);
  o[6] = (short)f2bf(b[2]); o[7] = (short)f2bf(b[3]);
  *(sx8*)(d + i) = o;
}

// ---------------- GEMM body: C = alpha*(A[M,K] @ B[N,K]^T + bias) ------------
// MODE 0: bf16 row-major C.  MODE 1: f32 row-major C.
// MODE 2: bf16 V^T output Vt[b][d][kl] with 8B-half swap when (d&8).
// MT: 128 (4 waves 2x2, acc 4x4) or 64 (4 waves 1x4, acc 4x2).
// bf16 A via global_load_lds w16, BK=64, XOR-swizzled LDS, MFMA 16x16x32.
template <int MODE, int MT>
__device__ __forceinline__ void gemm_body(short* sA, short* sB,
                                          const short* __restrict__ A,
                                          const short* __restrict__ Bw,
                                          const float* __restrict__ bias,
                                          void* __restrict__ Cptr, int M, int N,
                                          int K, float alpha, int bx) {
  const int t = threadIdx.x;
  const int lane = t & 63;
  const int w = t >> 6;
  const int quad = lane >> 4;
  const int l16 = lane & 15;
  const int x7 = l16 & 7;
  const int ntile = N >> 7;
  const int n0 = (bx % ntile) << 7;
  const int m0 = (bx / ntile) * MT;
  constexpr int NI = (MT == 128) ? 4 : 2;
  const int wm = (MT == 128) ? ((w >> 1) << 6) : 0;
  const int wn = (MT == 128) ? ((w & 1) << 6) : (w << 5);
  const fx4 fzero = {0.f, 0.f, 0.f, 0.f};
  fx4 acc[4][NI];
#pragma unroll
  for (int i = 0; i < 4; i++)
#pragma unroll
    for (int j = 0; j < NI; j++) acc[i][j] = fzero;

  const int srow = lane >> 3;
  const int scb = lane & 7;

  for (int k0 = 0; k0 < K; k0 += 64) {
    __syncthreads();
    if (MT == 128) {
#pragma unroll
      for (int j = 0; j < 4; j++) {
        const int row = w * 32 + j * 8 + srow;
        const int cb = scb ^ (row & 7);
        glds16(A + (size_t)(m0 + row) * K + k0 + cb * 8, &sA[(w * 32 + j * 8) * 64]);
      }
    } else {
#pragma unroll
      for (int j = 0; j < 2; j++) {
        const int row = j * 32 + w * 8 + srow;
        const int cb = scb ^ (row & 7);
        glds16(A + (size_t)(m0 + row) * K + k0 + cb * 8, &sA[(j * 32 + w * 8) * 64]);
      }
    }
#pragma unroll
    for (int j = 0; j < 4; j++) {
      const int row = w * 32 + j * 8 + srow;
      const int cb = scb ^ (row & 7);
      glds16(Bw + (size_t)(n0 + row) * K + k0 + cb * 8, &sB[(w * 32 + j * 8) * 64]);
    }
    __syncthreads();
#pragma unroll
    for (int kc = 0; kc < 2; kc++) {
      const int cbp = ((kc * 4 + quad) ^ x7) * 8;
      sx8 fa[4], fb[NI];
#pragma unroll
      for (int i = 0; i < 4; i++)
        fa[i] = *(const sx8*)(&sA[(wm + i * 16 + l16) * 64 + cbp]);
#pragma unroll
      for (int i = 0; i < NI; i++)
        fb[i] = *(const sx8*)(&sB[(wn + i * 16 + l16) * 64 + cbp]);
#pragma unroll
      for (int mi = 0; mi < 4; mi++)
#pragma unroll
        for (int ni = 0; ni < NI; ni++)
          acc[mi][ni] = MFMA32(fa[mi], fb[ni], acc[mi][ni]);
    }
  }
  // epilogue: C/D layout col=lane&15, row=quad*4+reg
#pragma unroll
  for (int ni = 0; ni < NI; ni++) {
    const int col = n0 + wn + ni * 16 + l16;
    const float bval = bias[col];
    if (MODE == 2) {
#pragma unroll
      for (int mi = 0; mi < 4; mi++) {
        const int rowb = m0 + wm + mi * 16 + quad * 4;
        const int bb = rowb >> 13;
        const int kl = (rowb & 8191) ^ ((col & 8) ? 4 : 0);
        sx4 pkv;
#pragma unroll
        for (int r = 0; r < 4; r++) pkv[r] = (short)f2bf(acc[mi][ni][r] + bval);
        *(sx4*)((unsigned short*)Cptr + ((size_t)bb * 1024 + col) * 8192 + kl) = pkv;
      }
    } else {
#pragma unroll
      for (int mi = 0; mi < 4; mi++)
#pragma unroll
        for (int r = 0; r < 4; r++) {
          const int row = m0 + wm + mi * 16 + quad * 4 + r;
          const float v = (acc[mi][ni][r] + bval) * alpha;
          if (MODE == 1) ((float*)Cptr)[(size_t)row * N + col] = v;
          else ((unsigned short*)Cptr)[(size_t)row * N + col] = f2bf(v);
        }
    }
  }
}

// K-projection: grid 1024
__global__ __launch_bounds__(256) void k_gemm_k(const short* __restrict__ ck,
                                                const short* __restrict__ cwk,
                                                const float* __restrict__ bk,
                                                short* __restrict__ Kp) {
  __shared__ __align__(16) short smem[16384];
  gemm_body<0, 128>(smem, smem + 8192, ck, cwk, bk, Kp, 16384, 1024, 1024, 1.f,
                    blockIdx.x);
}

// V-projection (fused transpose) + Q-projection: grid 128 + 1024
__global__ __launch_bounds__(256) void k_proj_vq(
    const short* __restrict__ cv, const short* __restrict__ cwv,
    const float* __restrict__ bv, short* __restrict__ Vt,
    const short* __restrict__ cq, const short* __restrict__ cwq,
    const float* __restrict__ bq, short* __restrict__ Qp, float alpha_q) {
  __shared__ __align__(16) short smem[16384];
  const int bx = blockIdx.x;
  if (bx < 128)
    gemm_body<0, 64>(smem, smem + 8192, cq, cwq, bq, Qp, 1024, 1024, 1024,
                     alpha_q, bx);
  else
    gemm_body<2, 128>(smem, smem + 8192, cv, cwv, bv, Vt, 16384, 1024, 1024,
                      1.f, bx - 128);
}

// out-projection: grid 128
__global__ __launch_bounds__(256) void k_gemm_out(const short* __restrict__ summed,
                                                  const short* __restrict__ cwf,
                                                  const float* __restrict__ bf,
                                                  float* __restrict__ out) {
  __shared__ __align__(16) short smem[16384];
  gemm_body<1, 64>(smem, smem + 8192, summed, cwf, bf, out, 1024, 1024, 1024,
                   1.f, blockIdx.x);
}

// ---------------- flash attention (S^T trick, no-max softmax) ----------------
// grid 1024, XCD-swizzled: x = (g&7) + 8*(qt + 8*(g>>3)), g=(b*8+h)*8+s.
__global__ __launch_bounds__(256, 4) void k_attn(const short* __restrict__ Qp,
                                                 const short* __restrict__ Kp,
                                                 const short* __restrict__ Vt,
                                                 const u64* __restrict__ mb,
                                                 float* __restrict__ ml,
                                                 float* __restrict__ Op) {
  __shared__ __align__(16) short sK[8192];  // 64 keys x 128 d (256B rows, swizzled)
  __shared__ __align__(16) short sV[8192];  // 128 d x 64 keys (128B rows, swizzled)
  const int x = blockIdx.x;
  const int gl = x & 7;
  const int qt = (x >> 3) & 7;
  const int gh = x >> 6;
  const int g = gh * 8 + gl;  // 0..127
  const int s = g & 7;
  const int h = (g >> 3) & 7;
  const int b = g >> 6;
  const int li = ((b * 8 + h) * 8 + qt) * 8 + s;  // logical index for ml/Op
  const int t = threadIdx.x;
  const int lane = t & 63;
  const int w = t >> 6;
  const int quad = lane >> 4;
  const int l16 = lane & 15;
  const int x7 = l16 & 7;
  const int q0 = qt << 6;
  const fx4 fzero = {0.f, 0.f, 0.f, 0.f};

  const short* qbase = Qp + (size_t)(b * 512 + q0 + w * 16 + l16) * 1024 + h * 128;
  sx8 aq[4];
#pragma unroll
  for (int kc = 0; kc < 4; kc++) aq[kc] = *(const sx8*)(qbase + kc * 32 + quad * 8);

  fx4 Ot[8];
#pragma unroll
  for (int d = 0; d < 8; d++) Ot[d] = fzero;
  float lsum = 0.f;

  const short* kbase = Kp + (size_t)(b * 8192 + s * 1024) * 1024 + h * 128;
  const short* vbase = Vt + (size_t)(b * 1024 + h * 128) * 8192 + s * 1024;
  const u64* wdp = mb + (size_t)(b * 512 + q0 + w * 16 + l16) * 128 + s * 16;
  const int srow4 = lane >> 4, scb16 = lane & 15;
  const int srow8 = lane >> 3, scb8 = lane & 7;
  const int h4 = ((quad & 1) ^ ((l16 >> 3) & 1)) * 4;  // 8B-half parity (bank spread)

  for (int kt = 0; kt < 16; kt++) {
    __syncthreads();
#pragma unroll
    for (int j = 0; j < 4; j++) {  // K tile: 4 rows/issue
      const int row = (w * 4 + j) * 4 + srow4;
      const int cb = scb16 ^ (row & 7);
      glds16(kbase + (size_t)(kt * 64 + row) * 1024 + cb * 8, &sK[(w * 4 + j) * 512]);
    }
#pragma unroll
    for (int j = 0; j < 4; j++) {  // V^T tile: 8 rows/issue
      const int row = (w * 4 + j) * 8 + srow8;
      const int cb = scb8 ^ (row & 7);
      glds16(vbase + (size_t)row * 8192 + kt * 64 + cb * 8, &sV[(w * 4 + j) * 512]);
    }
    const u64 wd = wdp[kt];
    __syncthreads();
    const unsigned lo = (unsigned)wd, hi = (unsigned)(wd >> 32);
    sx4 pk[4];
#pragma unroll
    for (int nt = 0; nt < 4; nt++) {
      fx4 a = fzero;
#pragma unroll
      for (int kc = 0; kc < 4; kc++) {
        const sx8 kf = *(const sx8*)(&sK[(nt * 16 + l16) * 128 + ((kc * 4 + quad) ^ x7) * 8]);
        a = MFMA32(kf, aq[kc], a);  // S^T: row=key, col=q
      }
      const unsigned bits = (nt & 2) ? hi : lo;
      const int sh = (nt & 1) * 16 + quad * 4;
      float pv[4];
#pragma unroll
      for (int r = 0; r < 4; r++) {
        const float e = __builtin_amdgcn_exp2f(a[r]);  // scale*log2e folded into Qp
        pv[r] = ((bits >> (sh + r)) & 1u) ? e : 0.f;
        lsum += pv[r];
      }
      sx4 pko;
      ((unsigned*)&pko)[0] = __builtin_amdgcn_perm(
          __float_as_uint(pv[1]) + 0x8000u, __float_as_uint(pv[0]) + 0x8000u, 0x07060302u);
      ((unsigned*)&pko)[1] = __builtin_amdgcn_perm(
          __float_as_uint(pv[3]) + 0x8000u, __float_as_uint(pv[2]) + 0x8000u, 0x07060302u);
      pk[nt] = pko;
    }
#pragma unroll
    for (int dt = 0; dt < 8; dt++) {
      fx4 o = Ot[dt];
#pragma unroll
      for (int nt = 0; nt < 4; nt++) {
        const int cb = (2 * nt + (quad >> 1)) ^ x7;
        const sx4 vf = *(const sx4*)(&sV[(dt * 16 + l16) * 64 + cb * 8 + h4]);
        o = MFMA16(vf, pk[nt], o);  // O^T: row=d, col=q
      }
      Ot[dt] = o;
    }
  }
  lsum += __shfl_xor(lsum, 16, 64);
  lsum += __shfl_xor(lsum, 32, 64);
  if (lane < 16) ml[(size_t)li * 64 + w * 16 + l16] = lsum;
  float* ob = Op + (size_t)li * 8192 + (w * 16 + l16) * 128 + quad * 4;
#pragma unroll
  for (int dt = 0; dt < 8; dt++) *(fx4*)(ob + dt * 16) = Ot[dt];
}

// ---------------- combine 8 KL-split partials -> summed bf16 -----------------
__global__ __launch_bounds__(256) void k_combine(const float* __restrict__ ml,
                                                 const float* __restrict__ Op,
                                                 short* __restrict__ summed) {
  const int xc = blockIdx.x;  // qt + 8*h + 64*b
  const int qt = xc & 7;
  const int h = (xc >> 3) & 7;
  const int b = xc >> 6;
  const int t = threadIdx.x;
  const int row = t >> 2;
  const int dg = (t & 3) * 32;
  float L = 0.f;
#pragma unroll
  for (int s = 0; s < 8; s++) L += ml[(size_t)(xc * 8 + s) * 64 + row];
  float o[32];
#pragma unroll
  for (int i = 0; i < 32; i++) o[i] = 0.f;
  if (L != 0.f) {
#pragma unroll
    for (int s = 0; s < 8; s++) {
      const float* src = Op + (size_t)(xc * 8 + s) * 8192 + row * 128 + dg;
#pragma unroll
      for (int i = 0; i < 8; i++) {
        const fx4 v = *(const fx4*)(src + i * 4);
        o[i * 4 + 0] += v[0]; o[i * 4 + 1] += v[1];
        o[i * 4 + 2] += v[2]; o[i * 4 + 3] += v[3];
      }
    }
    const float inv = 1.f / L;
#pragma unroll
    for (int i = 0; i < 32; i++) o[i] *= inv;
  }
  short* dst = summed + (size_t)(b * 512 + qt * 64 + row) * 1024 + h * 128 + dg;
#pragma unroll
  for (int i = 0; i < 4; i++) {
    sx8 pkv;
#pragma unroll
    for (int j = 0; j < 8; j++) pkv[j] = (short)f2bf(o[i * 8 + j]);
    *(sx8*)(dst + i * 8) = pkv;
  }
}

// ---------------- host ------------------------------------------------------
extern "C" void kernel_launch(void* const* d_in, const int* in_sizes, int n_in,
                              void* d_out, int out_size, void* d_ws, size_t ws_size,
                              hipStream_t stream) {
  (void)in_sizes; (void)n_in; (void)out_size; (void)ws_size;
  const float* inq = (const float*)d_in[0];
  const float* ink = (const float*)d_in[1];
  const float* inv = (const float*)d_in[2];
  const int* mask = (const int*)d_in[3];
  const float* Wq = (const float*)d_in[4];
  const float* bq = (const float*)d_in[5];
  const float* Wk = (const float*)d_in[6];
  const float* bk = (const float*)d_in[7];
  const float* Wv = (const float*)d_in[8];
  const float* bv = (const float*)d_in[9];
  const float* Wf = (const float*)d_in[10];
  const float* bf = (const float*)d_in[11];

  char* ws = (char*)d_ws;
  short* S1 = (short*)(ws + 0);            // ck -> cv -> Op(f32) : 33.5MB
  short* Kp = (short*)(ws + 33554432);     // 33.5MB bf16
  short* Vt = (short*)(ws + 67108864);     // 33.5MB bf16 [2][1024][8192]
  short* cq = (short*)(ws + 100663296);    // 2MB each
  short* cwq = (short*)(ws + 102760448);
  short* cwk = (short*)(ws + 104857600);
  short* cwv = (short*)(ws + 106954752);
  short* cwf = (short*)(ws + 109051904);
  short* Qp = (short*)(ws + 111149056);
  short* summed = (short*)(ws + 113246208);
  u64* mb = (u64*)(ws + 115343360);
  float* ml = (float*)(ws + 116391936);

  const float alpha_q = 0.12751757f;  // (1/sqrt(128)) * log2(e)

  k_prep<<<18944, 256, 0, stream>>>(ink, inq, Wq, Wk, Wv, Wf, mask, S1, cq, cwq,
                                    cwk, cwv, cwf, mb);
  k_gemm_k<<<1024, 256, 0, stream>>>(S1, cwk, bk, Kp);
  k_conv<<<8192, 256, 0, stream>>>(inv, S1);  // cv
  k_proj_vq<<<1152, 256, 0, stream>>>(S1, cwv, bv, Vt, cq, cwq, bq, Qp, alpha_q);
  k_attn<<<1024, 256, 0, stream>>>(Qp, Kp, Vt, mb, ml, (float*)S1);  // -> ml, Op
  k_combine<<<128, 256, 0, stream>>>(ml, (const float*)S1, summed);
  k_gemm_out<<<128, 256, 0, stream>>>(summed, cwf, bf, (float*)d_out);
}

// Round 6
// 394.468 us; speedup vs baseline: 1.1139x; 1.0254x over previous
//
#include <hip/hip_runtime.h>
#include <hip/hip_bf16.h>
#include <math.h>

// B=2 QL=512 KL=8192 D=1024 H=8 HD=128
typedef __attribute__((ext_vector_type(4))) float fx4;
typedef __attribute__((ext_vector_type(4))) short sx4;
typedef __attribute__((ext_vector_type(8))) short sx8;
typedef unsigned long long u64;

#define MFMA16(a, b, c) __builtin_amdgcn_mfma_f32_16x16x16bf16_1k(a, b, c, 0, 0, 0)
#define MFMA32(a, b, c) __builtin_amdgcn_mfma_f32_16x16x32_bf16(a, b, c, 0, 0, 0)

__device__ __forceinline__ unsigned short f2bf(float f) {
  unsigned int u = __float_as_uint(f);
  return (unsigned short)((u + 0x7fffu + ((u >> 16) & 1u)) >> 16);  // RNE
}

// async global->LDS, 16B per lane; LDS dest is wave-uniform base + lane*16
typedef const __attribute__((address_space(1))) char* gc1p;
typedef __attribute__((address_space(3))) char* lc3p;
__device__ __forceinline__ void glds16(const void* g, const void* lds_uniform) {
  gc1p gp = (gc1p)(unsigned long long)(uintptr_t)g;
  lc3p lp = (lc3p)(unsigned)__builtin_amdgcn_readfirstlane((int)(unsigned)(uintptr_t)lds_uniform);
  __builtin_amdgcn_global_load_lds(gp, lp, 16, 0, 0);
}

// ---------------- prep: all f32->bf16 conversions + mask pack ----------------
// [0,8192): ink -> ck          (16.8M elems)
// [8192,16384): inv -> cv      (16.8M)
// [16384,16896): inq -> cq     (1M)
// [16896,18944): Wq,Wk,Wv,Wf   (1M each)
// [18944,27136): mask pack
__global__ __launch_bounds__(256) void k_prep(
    const float* __restrict__ ink, const float* __restrict__ inv,
    const float* __restrict__ inq, const float* __restrict__ Wq,
    const float* __restrict__ Wk, const float* __restrict__ Wv,
    const float* __restrict__ Wf, const int* __restrict__ mask, short* ck,
    short* cv, short* cq, short* cwq, short* cwk, short* cwv, short* cwf,
    u64* __restrict__ mb) {
  __shared__ unsigned char nib[256];
  const int bx = blockIdx.x;
  const int t = threadIdx.x;
  if (bx >= 18944) {  // mask pack: 16B/lane loads, nibble assembly via LDS
    const int mbx = bx - 18944;
    const int4 m = *(const int4*)(mask + (size_t)mbx * 1024 + t * 4);
    nib[t] = (unsigned char)((m.x != 0) | ((m.y != 0) << 1) | ((m.z != 0) << 2) |
                             ((m.w != 0) << 3));
    __syncthreads();
    if (t < 16) {
      u64 wv = 0;
#pragma unroll
      for (int i = 0; i < 16; i++) wv |= (u64)(nib[t * 16 + i] & 0xF) << (4 * i);
      mb[(size_t)mbx * 16 + t] = wv;
    }
    return;
  }
  const float* s;
  short* d;
  size_t i;
  if (bx < 8192) {
    s = ink; d = ck; i = (size_t)bx * 2048;
  } else if (bx < 16384) {
    s = inv; d = cv; i = (size_t)(bx - 8192) * 2048;
  } else if (bx < 16896) {
    s = inq; d = cq; i = (size_t)(bx - 16384) * 2048;
  } else {
    const int r = bx - 16896;
    const int seg = r >> 9;
    s = seg == 0 ? Wq : seg == 1 ? Wk : seg == 2 ? Wv : Wf;
    d = seg == 0 ? cwq : seg == 1 ? cwk : seg == 2 ? cwv : cwf;
    i = (size_t)(r & 511) * 2048;
  }
  i += (size_t)t * 8;
  const fx4 a = *(const fx4*)(s + i);
  const fx4 b = *(const fx4*)(s + i + 4);
  sx8 o;
  o[0] = (short)f2bf(a[0]); o[1] = (short)f2bf(a[1]);
  o[2] = (short)f2bf(a[2]); o[3] = (short)f2bf(a[3]);
  o[4] = (short)f2bf(b[0]); o[5] = (short)f2bf(b[1]);
  o[6] = (short)f2bf(b[2]); o[7] = (short)f2bf(b[3]);
  *(sx8*)(d + i) = o;
}

// ---------------- GEMM body: C = alpha*(A[M,K] @ B[N,K]^T + bias) ------------
// MODE 0: bf16 row-major C.  MODE 1: f32 row-major C.
// MODE 2: bf16 V^T output Vt[b][d][kl] with 8B-half swap when (d&8).
// MT: 128 (4 waves 2x2, acc 4x4) or 64 (4 waves 1x4, acc 4x2).
// bf16 A via global_load_lds w16, BK=64, XOR-swizzled LDS, MFMA 16x16x32.
// M>=8192: XCD swizzle — all 8 n-tiles of an A m-strip share bx%8 (one XCD).
template <int MODE, int MT>
__device__ __forceinline__ void gemm_body(short* sA, short* sB,
                                          const short* __restrict__ A,
                                          const short* __restrict__ Bw,
                                          const float* __restrict__ bias,
                                          void* __restrict__ Cptr, int M, int N,
                                          int K, float alpha, int bx) {
  const int t = threadIdx.x;
  const int lane = t & 63;
  const int w = t >> 6;
  const int quad = lane >> 4;
  const int l16 = lane & 15;
  const int x7 = l16 & 7;
  int m0, n0;
  if (M >= 8192) {
    const int ml = bx & 7, nn = (bx >> 3) & 7, mh = bx >> 6;
    m0 = (mh * 8 + ml) * MT;
    n0 = nn << 7;
  } else {
    const int ntile = N >> 7;
    n0 = (bx % ntile) << 7;
    m0 = (bx / ntile) * MT;
  }
  constexpr int NI = (MT == 128) ? 4 : 2;
  const int wm = (MT == 128) ? ((w >> 1) << 6) : 0;
  const int wn = (MT == 128) ? ((w & 1) << 6) : (w << 5);
  const fx4 fzero = {0.f, 0.f, 0.f, 0.f};
  fx4 acc[4][NI];
#pragma unroll
  for (int i = 0; i < 4; i++)
#pragma unroll
    for (int j = 0; j < NI; j++) acc[i][j] = fzero;

  const int srow = lane >> 3;
  const int scb = lane & 7;

  for (int k0 = 0; k0 < K; k0 += 64) {
    __syncthreads();
    if (MT == 128) {
#pragma unroll
      for (int j = 0; j < 4; j++) {
        const int row = w * 32 + j * 8 + srow;
        const int cb = scb ^ (row & 7);
        glds16(A + (size_t)(m0 + row) * K + k0 + cb * 8, &sA[(w * 32 + j * 8) * 64]);
      }
    } else {
#pragma unroll
      for (int j = 0; j < 2; j++) {
        const int row = j * 32 + w * 8 + srow;
        const int cb = scb ^ (row & 7);
        glds16(A + (size_t)(m0 + row) * K + k0 + cb * 8, &sA[(j * 32 + w * 8) * 64]);
      }
    }
#pragma unroll
    for (int j = 0; j < 4; j++) {
      const int row = w * 32 + j * 8 + srow;
      const int cb = scb ^ (row & 7);
      glds16(Bw + (size_t)(n0 + row) * K + k0 + cb * 8, &sB[(w * 32 + j * 8) * 64]);
    }
    __syncthreads();
#pragma unroll
    for (int kc = 0; kc < 2; kc++) {
      const int cbp = ((kc * 4 + quad) ^ x7) * 8;
      sx8 fa[4], fb[NI];
#pragma unroll
      for (int i = 0; i < 4; i++)
        fa[i] = *(const sx8*)(&sA[(wm + i * 16 + l16) * 64 + cbp]);
#pragma unroll
      for (int i = 0; i < NI; i++)
        fb[i] = *(const sx8*)(&sB[(wn + i * 16 + l16) * 64 + cbp]);
#pragma unroll
      for (int mi = 0; mi < 4; mi++)
#pragma unroll
        for (int ni = 0; ni < NI; ni++)
          acc[mi][ni] = MFMA32(fa[mi], fb[ni], acc[mi][ni]);
    }
  }
  // epilogue: C/D layout col=lane&15, row=quad*4+reg
#pragma unroll
  for (int ni = 0; ni < NI; ni++) {
    const int col = n0 + wn + ni * 16 + l16;
    const float bval = bias[col];
    if (MODE == 2) {
#pragma unroll
      for (int mi = 0; mi < 4; mi++) {
        const int rowb = m0 + wm + mi * 16 + quad * 4;
        const int bb = rowb >> 13;
        const int kl = (rowb & 8191) ^ ((col & 8) ? 4 : 0);
        sx4 pkv;
#pragma unroll
        for (int r = 0; r < 4; r++) pkv[r] = (short)f2bf(acc[mi][ni][r] + bval);
        *(sx4*)((unsigned short*)Cptr + ((size_t)bb * 1024 + col) * 8192 + kl) = pkv;
      }
    } else {
#pragma unroll
      for (int mi = 0; mi < 4; mi++)
#pragma unroll
        for (int r = 0; r < 4; r++) {
          const int row = m0 + wm + mi * 16 + quad * 4 + r;
          const float v = (acc[mi][ni][r] + bval) * alpha;
          if (MODE == 1) ((float*)Cptr)[(size_t)row * N + col] = v;
          else ((unsigned short*)Cptr)[(size_t)row * N + col] = f2bf(v);
        }
    }
  }
}

// K-projection: grid 1024
__global__ __launch_bounds__(256) void k_gemm_k(const short* __restrict__ ck,
                                                const short* __restrict__ cwk,
                                                const float* __restrict__ bk,
                                                short* __restrict__ Kp) {
  __shared__ __align__(16) short smem[16384];
  gemm_body<0, 128>(smem, smem + 8192, ck, cwk, bk, Kp, 16384, 1024, 1024, 1.f,
                    blockIdx.x);
}

// V-projection (fused transpose) + Q-projection: grid 128 + 1024
__global__ __launch_bounds__(256) void k_proj_vq(
    const short* __restrict__ cv, const short* __restrict__ cwv,
    const float* __restrict__ bv, short* __restrict__ Vt,
    const short* __restrict__ cq, const short* __restrict__ cwq,
    const float* __restrict__ bq, short* __restrict__ Qp, float alpha_q) {
  __shared__ __align__(16) short smem[16384];
  const int bx = blockIdx.x;
  if (bx < 128)
    gemm_body<0, 64>(smem, smem + 8192, cq, cwq, bq, Qp, 1024, 1024, 1024,
                     alpha_q, bx);
  else
    gemm_body<2, 128>(smem, smem + 8192, cv, cwv, bv, Vt, 16384, 1024, 1024,
                      1.f, bx - 128);
}

// out-projection: grid 128
__global__ __launch_bounds__(256) void k_gemm_out(const short* __restrict__ summed,
                                                  const short* __restrict__ cwf,
                                                  const float* __restrict__ bf,
                                                  float* __restrict__ out) {
  __shared__ __align__(16) short smem[16384];
  gemm_body<1, 64>(smem, smem + 8192, summed, cwf, bf, out, 1024, 1024, 1024,
                   1.f, blockIdx.x);
}

// ---------------- flash attention (S^T trick, no-max softmax) ----------------
// grid 1024, XCD-swizzled: x = (g&7) + 8*(qt + 8*(g>>3)), g=(b*8+h)*8+s.
__global__ __launch_bounds__(256, 4) void k_attn(const short* __restrict__ Qp,
                                                 const short* __restrict__ Kp,
                                                 const short* __restrict__ Vt,
                                                 const u64* __restrict__ mb,
                                                 float* __restrict__ ml,
                                                 float* __restrict__ Op) {
  __shared__ __align__(16) short sK[8192];  // 64 keys x 128 d (256B rows, swizzled)
  __shared__ __align__(16) short sV[8192];  // 128 d x 64 keys (128B rows, swizzled)
  const int x = blockIdx.x;
  const int gl = x & 7;
  const int qt = (x >> 3) & 7;
  const int gh = x >> 6;
  const int g = gh * 8 + gl;  // 0..127
  const int s = g & 7;
  const int h = (g >> 3) & 7;
  const int b = g >> 6;
  const int li = ((b * 8 + h) * 8 + qt) * 8 + s;  // logical index for ml/Op
  const int t = threadIdx.x;
  const int lane = t & 63;
  const int w = t >> 6;
  const int quad = lane >> 4;
  const int l16 = lane & 15;
  const int x7 = l16 & 7;
  const int q0 = qt << 6;
  const fx4 fzero = {0.f, 0.f, 0.f, 0.f};

  const short* qbase = Qp + (size_t)(b * 512 + q0 + w * 16 + l16) * 1024 + h * 128;
  sx8 aq[4];
#pragma unroll
  for (int kc = 0; kc < 4; kc++) aq[kc] = *(const sx8*)(qbase + kc * 32 + quad * 8);

  fx4 Ot[8];
#pragma unroll
  for (int d = 0; d < 8; d++) Ot[d] = fzero;
  float lsum = 0.f;

  const short* kbase = Kp + (size_t)(b * 8192 + s * 1024) * 1024 + h * 128;
  const short* vbase = Vt + (size_t)(b * 1024 + h * 128) * 8192 + s * 1024;
  const u64* wdp = mb + (size_t)(b * 512 + q0 + w * 16 + l16) * 128 + s * 16;
  const int srow4 = lane >> 4, scb16 = lane & 15;
  const int srow8 = lane >> 3, scb8 = lane & 7;
  const int h4 = ((quad & 1) ^ ((l16 >> 3) & 1)) * 4;  // 8B-half parity (bank spread)

  for (int kt = 0; kt < 16; kt++) {
    __syncthreads();
#pragma unroll
    for (int j = 0; j < 4; j++) {  // K tile: 4 rows/issue
      const int row = (w * 4 + j) * 4 + srow4;
      const int cb = scb16 ^ (row & 7);
      glds16(kbase + (size_t)(kt * 64 + row) * 1024 + cb * 8, &sK[(w * 4 + j) * 512]);
    }
#pragma unroll
    for (int j = 0; j < 4; j++) {  // V^T tile: 8 rows/issue
      const int row = (w * 4 + j) * 8 + srow8;
      const int cb = scb8 ^ (row & 7);
      glds16(vbase + (size_t)row * 8192 + kt * 64 + cb * 8, &sV[(w * 4 + j) * 512]);
    }
    const u64 wd = wdp[kt];
    __syncthreads();
    const unsigned lo = (unsigned)wd, hi = (unsigned)(wd >> 32);
    sx4 pk[4];
#pragma unroll
    for (int nt = 0; nt < 4; nt++) {
      fx4 a = fzero;
#pragma unroll
      for (int kc = 0; kc < 4; kc++) {
        const sx8 kf = *(const sx8*)(&sK[(nt * 16 + l16) * 128 + ((kc * 4 + quad) ^ x7) * 8]);
        a = MFMA32(kf, aq[kc], a);  // S^T: row=key, col=q
      }
      const unsigned bits = (nt & 2) ? hi : lo;
      const int sh = (nt & 1) * 16 + quad * 4;
      float pv[4];
#pragma unroll
      for (int r = 0; r < 4; r++) {
        const float e = __builtin_amdgcn_exp2f(a[r]);  // scale*log2e folded into Qp
        pv[r] = ((bits >> (sh + r)) & 1u) ? e : 0.f;
        lsum += pv[r];
      }
      sx4 pko;
      ((unsigned*)&pko)[0] = __builtin_amdgcn_perm(
          __float_as_uint(pv[1]) + 0x8000u, __float_as_uint(pv[0]) + 0x8000u, 0x07060302u);
      ((unsigned*)&pko)[1] = __builtin_amdgcn_perm(
          __float_as_uint(pv[3]) + 0x8000u, __float_as_uint(pv[2]) + 0x8000u, 0x07060302u);
      pk[nt] = pko;
    }
#pragma unroll
    for (int dt = 0; dt < 8; dt++) {
      fx4 o = Ot[dt];
#pragma unroll
      for (int nt = 0; nt < 4; nt++) {
        const int cb = (2 * nt + (quad >> 1)) ^ x7;
        const sx4 vf = *(const sx4*)(&sV[(dt * 16 + l16) * 64 + cb * 8 + h4]);
        o = MFMA16(vf, pk[nt], o);  // O^T: row=d, col=q
      }
      Ot[dt] = o;
    }
  }
  lsum += __shfl_xor(lsum, 16, 64);
  lsum += __shfl_xor(lsum, 32, 64);
  if (lane < 16) ml[(size_t)li * 64 + w * 16 + l16] = lsum;
  float* ob = Op + (size_t)li * 8192 + (w * 16 + l16) * 128 + quad * 4;
#pragma unroll
  for (int dt = 0; dt < 8; dt++) *(fx4*)(ob + dt * 16) = Ot[dt];
}

// ---------------- combine 8 KL-split partials -> summed bf16 -----------------
__global__ __launch_bounds__(256) void k_combine(const float* __restrict__ ml,
                                                 const float* __restrict__ Op,
                                                 short* __restrict__ summed) {
  const int xc = blockIdx.x;  // qt + 8*h + 64*b
  const int qt = xc & 7;
  const int h = (xc >> 3) & 7;
  const int b = xc >> 6;
  const int t = threadIdx.x;
  const int row = t >> 2;
  const int dg = (t & 3) * 32;
  float L = 0.f;
#pragma unroll
  for (int s = 0; s < 8; s++) L += ml[(size_t)(xc * 8 + s) * 64 + row];
  float o[32];
#pragma unroll
  for (int i = 0; i < 32; i++) o[i] = 0.f;
  if (L != 0.f) {
#pragma unroll
    for (int s = 0; s < 8; s++) {
      const float* src = Op + (size_t)(xc * 8 + s) * 8192 + row * 128 + dg;
#pragma unroll
      for (int i = 0; i < 8; i++) {
        const fx4 v = *(const fx4*)(src + i * 4);
        o[i * 4 + 0] += v[0]; o[i * 4 + 1] += v[1];
        o[i * 4 + 2] += v[2]; o[i * 4 + 3] += v[3];
      }
    }
    const float inv = 1.f / L;
#pragma unroll
    for (int i = 0; i < 32; i++) o[i] *= inv;
  }
  short* dst = summed + (size_t)(b * 512 + qt * 64 + row) * 1024 + h * 128 + dg;
#pragma unroll
  for (int i = 0; i < 4; i++) {
    sx8 pkv;
#pragma unroll
    for (int j = 0; j < 8; j++) pkv[j] = (short)f2bf(o[i * 8 + j]);
    *(sx8*)(dst + i * 8) = pkv;
  }
}

// ---------------- host ------------------------------------------------------
extern "C" void kernel_launch(void* const* d_in, const int* in_sizes, int n_in,
                              void* d_out, int out_size, void* d_ws, size_t ws_size,
                              hipStream_t stream) {
  (void)in_sizes; (void)n_in; (void)out_size; (void)ws_size;
  const float* inq = (const float*)d_in[0];
  const float* ink = (const float*)d_in[1];
  const float* inv = (const float*)d_in[2];
  const int* mask = (const int*)d_in[3];
  const float* Wq = (const float*)d_in[4];
  const float* bq = (const float*)d_in[5];
  const float* Wk = (const float*)d_in[6];
  const float* bk = (const float*)d_in[7];
  const float* Wv = (const float*)d_in[8];
  const float* bv = (const float*)d_in[9];
  const float* Wf = (const float*)d_in[10];
  const float* bf = (const float*)d_in[11];

  char* ws = (char*)d_ws;
  short* S1 = (short*)(ws + 0);            // ck -> Vt : 33.5MB
  short* Kp = (short*)(ws + 33554432);     // 33.5MB bf16
  short* S3 = (short*)(ws + 67108864);     // cv -> Op(f32) : 33.5MB
  short* cq = (short*)(ws + 100663296);    // 2MB each
  short* cwq = (short*)(ws + 102760448);
  short* cwk = (short*)(ws + 104857600);
  short* cwv = (short*)(ws + 106954752);
  short* cwf = (short*)(ws + 109051904);
  short* Qp = (short*)(ws + 111149056);
  short* summed = (short*)(ws + 113246208);
  u64* mb = (u64*)(ws + 115343360);
  float* ml = (float*)(ws + 116391936);

  const float alpha_q = 0.12751757f;  // (1/sqrt(128)) * log2(e)

  k_prep<<<27136, 256, 0, stream>>>(ink, inv, inq, Wq, Wk, Wv, Wf, mask, S1, S3,
                                    cq, cwq, cwk, cwv, cwf, mb);
  k_gemm_k<<<1024, 256, 0, stream>>>(S1, cwk, bk, Kp);
  k_proj_vq<<<1152, 256, 0, stream>>>(S3, cwv, bv, S1, cq, cwq, bq, Qp, alpha_q);
  k_attn<<<1024, 256, 0, stream>>>(Qp, Kp, S1, mb, ml, (float*)S3);  // -> ml, Op
  k_combine<<<128, 256, 0, stream>>>(ml, (const float*)S3, summed);
  k_gemm_out<<<128, 256, 0, stream>>>(summed, cwf, bf, (float*)d_out);
}